// Round 7
// baseline (885.054 us; speedup 1.0000x reference)
//
#include <hip/hip_runtime.h>
#include <math.h>

// RWKV6 block on MI355X. fp32 problem; GEMMs via split-bf16 (hi/lo) x3 MFMA emulation
// on mfma_f32_32x32x16_bf16. B=4, T=2048, C=2048. WKV via chunked parallel scan.
constexpr int B_ = 4;
constexpr int T_ = 2048;
constexpr int C_ = 2048;
constexpr int M_ = B_ * T_;          // 8192 rows
constexpr float EPS_ = 1e-5f;
constexpr int KSTEPS = C_ / 32;      // 64
constexpr int NCH = 32;              // scan chunks
constexpr int CHL = T_ / NCH;        // 64 steps/chunk

typedef __attribute__((ext_vector_type(8))) short short8;    // bf16x8 MFMA operand
typedef __attribute__((ext_vector_type(16))) float f32x16;   // 32x32 MFMA acc

__device__ __forceinline__ unsigned short rne_bf16(float x) {
    unsigned u = __float_as_uint(x);
    unsigned r = u + 0x7FFFu + ((u >> 16) & 1u);
    return (unsigned short)(r >> 16);
}
__device__ __forceinline__ void split_bf16(float x, unsigned short& hi, unsigned short& lo) {
    hi = rne_bf16(x);
    lo = rne_bf16(x - __uint_as_float((unsigned)hi << 16));
}

// ---------------- LayerNorm: one block per (b,t) row ----------------
__global__ __launch_bounds__(256) void ln_kernel(const float* __restrict__ x,
                                                 const float* __restrict__ w,
                                                 const float* __restrict__ bias,
                                                 float* __restrict__ xt) {
    const int row = blockIdx.x;
    const float* xr = x + (size_t)row * C_;
    const int tid = threadIdx.x;

    float4 v0 = ((const float4*)xr)[tid];
    float4 v1 = ((const float4*)xr)[tid + 256];

    float s = v0.x + v0.y + v0.z + v0.w + v1.x + v1.y + v1.z + v1.w;
    float q = v0.x*v0.x + v0.y*v0.y + v0.z*v0.z + v0.w*v0.w
            + v1.x*v1.x + v1.y*v1.y + v1.z*v1.z + v1.w*v1.w;

    #pragma unroll
    for (int off = 32; off > 0; off >>= 1) {
        s += __shfl_down(s, off, 64);
        q += __shfl_down(q, off, 64);
    }
    __shared__ float red[10];
    const int wid = tid >> 6, lane = tid & 63;
    if (lane == 0) { red[wid * 2] = s; red[wid * 2 + 1] = q; }
    __syncthreads();
    if (tid == 0) {
        float ts = 0.f, tq = 0.f;
        #pragma unroll
        for (int i = 0; i < 4; ++i) { ts += red[i * 2]; tq += red[i * 2 + 1]; }
        const float mu = ts / (float)C_;
        const float var = tq / (float)C_ - mu * mu;
        red[8] = mu;
        red[9] = rsqrtf(var + EPS_);
    }
    __syncthreads();
    const float mu = red[8], rstd = red[9];

    float4 w0 = ((const float4*)w)[tid];
    float4 w1 = ((const float4*)w)[tid + 256];
    float4 b0 = ((const float4*)bias)[tid];
    float4 b1 = ((const float4*)bias)[tid + 256];

    float4 o0, o1;
    o0.x = (v0.x - mu) * rstd * w0.x + b0.x;
    o0.y = (v0.y - mu) * rstd * w0.y + b0.y;
    o0.z = (v0.z - mu) * rstd * w0.z + b0.z;
    o0.w = (v0.w - mu) * rstd * w0.w + b0.w;
    o1.x = (v1.x - mu) * rstd * w1.x + b1.x;
    o1.y = (v1.y - mu) * rstd * w1.y + b1.y;
    o1.z = (v1.z - mu) * rstd * w1.z + b1.z;
    o1.w = (v1.w - mu) * rstd * w1.w + b1.w;

    float* outr = xt + (size_t)row * C_;
    ((float4*)outr)[tid] = o0;
    ((float4*)outr)[tid + 256] = o1;
}

// ---------------- time-mix + split to bf16 hi/lo planes ----------------
__global__ __launch_bounds__(256) void mixsplit_kernel(const float* __restrict__ xt,
                                                       const float* __restrict__ mix,
                                                       unsigned short* __restrict__ hi,
                                                       unsigned short* __restrict__ lo) {
    const int i = blockIdx.x * 256 + threadIdx.x;   // over M_*C_/4 float4s
    const int m = i >> 9;                           // C_/4 = 512
    const int c4 = i & 511;
    const float4 cur = ((const float4*)xt)[i];
    const float4 mx = ((const float4*)mix)[c4];
    float4 prev = make_float4(0.f, 0.f, 0.f, 0.f);
    if ((m & (T_ - 1)) != 0) prev = ((const float4*)xt)[i - 512];
    float4 a;
    a.x = prev.x + (cur.x - prev.x) * mx.x;
    a.y = prev.y + (cur.y - prev.y) * mx.y;
    a.z = prev.z + (cur.z - prev.z) * mx.z;
    a.w = prev.w + (cur.w - prev.w) * mx.w;
    ushort4 h, l;
    split_bf16(a.x, h.x, l.x);
    split_bf16(a.y, h.y, l.y);
    split_bf16(a.z, h.z, l.z);
    split_bf16(a.w, h.w, l.w);
    ((ushort4*)hi)[i] = h;
    ((ushort4*)lo)[i] = l;
}

// ---------------- W fp32 -> (hi, lo) bf16 planes ----------------
__global__ __launch_bounds__(256) void wconv_kernel(const float* __restrict__ W,
                                                    unsigned short* __restrict__ hi,
                                                    unsigned short* __restrict__ lo) {
    const int i = blockIdx.x * 256 + threadIdx.x;   // over C_*C_/4 float4s
    float4 w = ((const float4*)W)[i];
    ushort4 h, l;
    split_bf16(w.x, h.x, l.x);
    split_bf16(w.y, h.y, l.y);
    split_bf16(w.z, h.z, l.z);
    split_bf16(w.w, h.w, l.w);
    ((ushort4*)hi)[i] = h;
    ((ushort4*)lo)[i] = l;
}

// ---------------- MFMA GEMM: Y[m,n] = sum_k A[m,k] * W[n,k] --------------
// acc += Ah*Wh + Al*Wh + Ah*Wl on mfma_f32_32x32x16_bf16.
// 256x256 tile, BK=32, 512 threads (8 waves, 2Mx4N; 128x64 per wave as
// 4mi x 2ni tiles of 32x32). 128KB LDS double-buffer; per region 256 rows x
// 8 slots of 16B (slots 0-3 hi k-chunks, 4-7 lo), phys slot = s ^ (row&7);
// global_load_lds dest linear, per-lane GLOBAL source pre-applies inverse swizzle.
// 4 phases per K-step (one mi each, 12 MFMA), counted vmcnt, setprio.
template <bool SIG>
__global__ __launch_bounds__(512, 2) void gemm_mfma(const unsigned short* __restrict__ Ahi,
                                                    const unsigned short* __restrict__ Alo,
                                                    const unsigned short* __restrict__ Whi,
                                                    const unsigned short* __restrict__ Wlo,
                                                    float* __restrict__ Y) {
    __shared__ unsigned short lds[2][2][256 * 64];

    const int tid = threadIdx.x;
    const int lane = tid & 63;
    const int wid = tid >> 6;          // 0..7
    const int wr = wid >> 2;           // 0..1  (M half: 128 rows)
    const int wcn = wid & 3;           // 0..3  (N quarter: 64 cols)

    // XCD-chunked block swizzle: 256 blocks, 8 XCDs, 32/XCD
    const int bid = blockIdx.x;
    const int swz = (bid & 7) * 32 + (bid >> 3);
    const int m0 = (swz >> 3) * 256;
    const int n0 = (swz & 7) * 256;

    const unsigned short* gA[4];
    const unsigned short* gB[4];
    #pragma unroll
    for (int j = 0; j < 4; ++j) {
        const int ci = j * 512 + tid;
        const int r = ci >> 3, p = ci & 7;
        const int s = p ^ (r & 7);
        const int pl = s >> 2, ks = s & 3;
        gA[j] = (pl ? Alo : Ahi) + (size_t)(m0 + r) * C_ + ks * 8;
        gB[j] = (pl ? Wlo : Whi) + (size_t)(n0 + r) * C_ + ks * 8;
    }
    const int stage_off = wid * 512;

    // ---- 32x32x16 fragment addressing ----
    // lane reads 8 consecutive bf16 at row (lane&31), k-chunk kq=(lane>>5)
    // within each K=16 sub-step; chunk c = ksub*2+kq; slot = plane*4+c.
    const int l31 = lane & 31;
    const int kq = lane >> 5;
    const int x7 = l31 & 7;
    const int pH0 = (0 + kq) ^ x7;     // hi, ksub0
    const int pH1 = (2 + kq) ^ x7;     // hi, ksub1
    const int pL0 = (4 + kq) ^ x7;     // lo, ksub0
    const int pL1 = (6 + kq) ^ x7;     // lo, ksub1
    const int rowA = (wr * 128 + l31) * 64;     // + mi*32*64
    const int rowB = (wcn * 64 + l31) * 64;     // + ni*32*64

    f32x16 acc[4][2] = {};

    auto ISSUE = [&](int buf, int t, int j) {
        const int ko = t * 32;
        __builtin_amdgcn_global_load_lds(
            (const __attribute__((address_space(1))) unsigned int*)(gA[j] + ko),
            (__attribute__((address_space(3))) unsigned int*)&lds[buf][0][j * 4096 + stage_off],
            16, 0, 0);
        __builtin_amdgcn_global_load_lds(
            (const __attribute__((address_space(1))) unsigned int*)(gB[j] + ko),
            (__attribute__((address_space(3))) unsigned int*)&lds[buf][1][j * 4096 + stage_off],
            16, 0, 0);
    };

    // prologue: stage tile 0 (8 loads/thread)
    #pragma unroll
    for (int j = 0; j < 4; ++j) ISSUE(0, 0, j);

    for (int t = 0; t < KSTEPS; ++t) {
        const int cur = t & 1, nxt = cur ^ 1;
        const bool last = (t == KSTEPS - 1);
        const unsigned short* LA = lds[cur][0];
        const unsigned short* LB = lds[cur][1];

        short8 bh[2][2], bl[2][2];   // [ni][ksub]

        // ---------- phase 0 (mi=0): validate buf cur, read B frags ----------
        if (!last) {
            ISSUE(nxt, t + 1, 0);
            asm volatile("s_waitcnt vmcnt(2)" ::: "memory");  // tile t's 8 done
        } else {
            asm volatile("s_waitcnt vmcnt(0)" ::: "memory");
        }
        __builtin_amdgcn_s_barrier();
        #pragma unroll
        for (int ni = 0; ni < 2; ++ni) {
            bh[ni][0] = *(const short8*)&LB[rowB + ni * 2048 + pH0 * 8];
            bh[ni][1] = *(const short8*)&LB[rowB + ni * 2048 + pH1 * 8];
            bl[ni][0] = *(const short8*)&LB[rowB + ni * 2048 + pL0 * 8];
            bl[ni][1] = *(const short8*)&LB[rowB + ni * 2048 + pL1 * 8];
        }
        {
            const short8 ah0 = *(const short8*)&LA[rowA + pH0 * 8];
            const short8 ah1 = *(const short8*)&LA[rowA + pH1 * 8];
            const short8 al0 = *(const short8*)&LA[rowA + pL0 * 8];
            const short8 al1 = *(const short8*)&LA[rowA + pL1 * 8];
            asm volatile("s_waitcnt lgkmcnt(0)" ::: "memory");
            __builtin_amdgcn_s_setprio(1);
            #pragma unroll
            for (int ni = 0; ni < 2; ++ni) {
                acc[0][ni] = __builtin_amdgcn_mfma_f32_32x32x16_bf16(ah0, bh[ni][0], acc[0][ni], 0, 0, 0);
                acc[0][ni] = __builtin_amdgcn_mfma_f32_32x32x16_bf16(al0, bh[ni][0], acc[0][ni], 0, 0, 0);
                acc[0][ni] = __builtin_amdgcn_mfma_f32_32x32x16_bf16(ah0, bl[ni][0], acc[0][ni], 0, 0, 0);
                acc[0][ni] = __builtin_amdgcn_mfma_f32_32x32x16_bf16(ah1, bh[ni][1], acc[0][ni], 0, 0, 0);
                acc[0][ni] = __builtin_amdgcn_mfma_f32_32x32x16_bf16(al1, bh[ni][1], acc[0][ni], 0, 0, 0);
                acc[0][ni] = __builtin_amdgcn_mfma_f32_32x32x16_bf16(ah1, bl[ni][1], acc[0][ni], 0, 0, 0);
            }
            __builtin_amdgcn_s_setprio(0);
        }
        __builtin_amdgcn_s_barrier();

        // ---------- phases 1..3 (mi = 1,2,3) ----------
        #pragma unroll
        for (int p = 1; p < 4; ++p) {
            const int aoff = rowA + p * 2048;   // mi*32 rows * 64 ushorts
            const short8 ah0 = *(const short8*)&LA[aoff + pH0 * 8];
            const short8 ah1 = *(const short8*)&LA[aoff + pH1 * 8];
            const short8 al0 = *(const short8*)&LA[aoff + pL0 * 8];
            const short8 al1 = *(const short8*)&LA[aoff + pL1 * 8];
            if (!last) ISSUE(nxt, t + 1, p);
            __builtin_amdgcn_s_barrier();
            asm volatile("s_waitcnt lgkmcnt(0)" ::: "memory");
            __builtin_amdgcn_s_setprio(1);
            #pragma unroll
            for (int ni = 0; ni < 2; ++ni) {
                acc[p][ni] = __builtin_amdgcn_mfma_f32_32x32x16_bf16(ah0, bh[ni][0], acc[p][ni], 0, 0, 0);
                acc[p][ni] = __builtin_amdgcn_mfma_f32_32x32x16_bf16(al0, bh[ni][0], acc[p][ni], 0, 0, 0);
                acc[p][ni] = __builtin_amdgcn_mfma_f32_32x32x16_bf16(ah0, bl[ni][0], acc[p][ni], 0, 0, 0);
                acc[p][ni] = __builtin_amdgcn_mfma_f32_32x32x16_bf16(ah1, bh[ni][1], acc[p][ni], 0, 0, 0);
                acc[p][ni] = __builtin_amdgcn_mfma_f32_32x32x16_bf16(al1, bh[ni][1], acc[p][ni], 0, 0, 0);
                acc[p][ni] = __builtin_amdgcn_mfma_f32_32x32x16_bf16(ah1, bl[ni][1], acc[p][ni], 0, 0, 0);
            }
            __builtin_amdgcn_s_setprio(0);
            __builtin_amdgcn_s_barrier();
        }
    }

    // ---- epilogue: 32x32 C/D layout col=lane&31, row=(reg&3)+8*(reg>>2)+4*(lane>>5)
    const int ocol0 = n0 + wcn * 64 + l31;
    const int orow0 = m0 + wr * 128 + 4 * kq;
    #pragma unroll
    for (int mi = 0; mi < 4; ++mi)
        #pragma unroll
        for (int ni = 0; ni < 2; ++ni)
            #pragma unroll
            for (int rr = 0; rr < 16; ++rr) {
                float v = acc[mi][ni][rr];
                if (SIG) v = 1.f / (1.f + expf(-v));
                const int row = orow0 + mi * 32 + (rr & 3) + 8 * (rr >> 2);
                Y[(size_t)row * C_ + ocol0 + ni * 32] = v;
            }
}

// ---------------- WKV chunked scan, pass 1: per-chunk local end state ----
__global__ __launch_bounds__(256) void wkv_scan1(const float* __restrict__ k,
                                                 const float* __restrict__ time_decay,
                                                 float* __restrict__ chend) {
    const int c0 = (blockIdx.x * 256 + threadIdx.x) * 2;
    const int j = blockIdx.y;
    const int b = blockIdx.z;
    const float2 td = *(const float2*)&time_decay[c0];
    const float d0 = 1.f / (1.f + expf(-td.x));
    const float d1 = 1.f / (1.f + expf(-td.y));
    size_t base = ((size_t)b * T_ + (size_t)j * CHL) * C_ + c0;
    float s0 = 0.f, s1 = 0.f;
    #pragma unroll 8
    for (int t = 0; t < CHL; ++t) {
        const float2 kt = *(const float2*)&k[base];
        s0 = s0 * d0 + kt.x;
        s1 = s1 * d1 + kt.y;
        base += C_;
    }
    *(float2*)&chend[((size_t)b * NCH + j) * C_ + c0] = make_float2(s0, s1);
}

// ---------------- WKV chunked scan, pass 2: carry-in + rescan + fuse -----
__global__ __launch_bounds__(256) void wkv_scan2(const float* __restrict__ k,
                                                 const float* __restrict__ v,
                                                 const float* __restrict__ r,
                                                 const float* __restrict__ time_decay,
                                                 const float* __restrict__ time_first,
                                                 const float* __restrict__ chend,
                                                 unsigned short* __restrict__ yhi,
                                                 unsigned short* __restrict__ ylo) {
    const int c0 = (blockIdx.x * 256 + threadIdx.x) * 2;
    const int j = blockIdx.y;
    const int b = blockIdx.z;
    const float2 td = *(const float2*)&time_decay[c0];
    const float2 tf = *(const float2*)&time_first[c0];
    const float d0 = 1.f / (1.f + expf(-td.x));
    const float d1 = 1.f / (1.f + expf(-td.y));
    const float f0 = expf(tf.x);
    const float f1 = expf(tf.y);

    float dL0 = d0, dL1 = d1;           // d^CHL, CHL=64 -> 6 squarings
    #pragma unroll
    for (int i = 0; i < 6; ++i) { dL0 *= dL0; dL1 *= dL1; }

    float s0 = 0.f, s1 = 0.f;
    for (int i = 0; i < j; ++i) {
        const float2 e = *(const float2*)&chend[((size_t)b * NCH + i) * C_ + c0];
        s0 = s0 * dL0 + e.x;
        s1 = s1 * dL1 + e.y;
    }

    size_t base = ((size_t)b * T_ + (size_t)j * CHL) * C_ + c0;
    #pragma unroll 4
    for (int t = 0; t < CHL; ++t) {
        const float2 kt = *(const float2*)&k[base];
        const float2 vt = *(const float2*)&v[base];
        const float2 rt = *(const float2*)&r[base];
        s0 = s0 * d0 + kt.x;
        s1 = s1 * d1 + kt.y;
        const float y0 = rt.x * ((s0 * f0 + kt.x) * vt.x);
        const float y1 = rt.y * ((s1 * f1 + kt.y) * vt.y);
        unsigned short h0, l0, h1, l1;
        split_bf16(y0, h0, l0);
        split_bf16(y1, h1, l1);
        ushort2 ph; ph.x = h0; ph.y = h1;
        ushort2 pl; pl.x = l0; pl.y = l1;
        *(ushort2*)&yhi[base] = ph;
        *(ushort2*)&ylo[base] = pl;
        base += C_;
    }
}

// ---------------- launch ----------------
extern "C" void kernel_launch(void* const* d_in, const int* in_sizes, int n_in,
                              void* d_out, int out_size, void* d_ws, size_t ws_size,
                              hipStream_t stream) {
    const float* x          = (const float*)d_in[0];
    const float* ln_w       = (const float*)d_in[1];
    const float* ln_b       = (const float*)d_in[2];
    const float* mix_k      = (const float*)d_in[3];
    const float* mix_v      = (const float*)d_in[4];
    const float* mix_r      = (const float*)d_in[5];
    const float* time_decay = (const float*)d_in[6];
    const float* time_first = (const float*)d_in[7];
    const float* Wk         = (const float*)d_in[8];
    const float* Wv         = (const float*)d_in[9];
    const float* Wr         = (const float*)d_in[10];
    const float* Wo         = (const float*)d_in[11];
    float* out = (float*)d_out;

    // ws (211.8 MB): xt/vb 64MB | A planes hi+lo 67MB | kb 64MB | W planes 16.8MB
    const size_t planeElems = (size_t)M_ * C_;
    float* xt = (float*)d_ws;                                   // later reused as vb
    unsigned short* aphi = (unsigned short*)(xt + planeElems);
    unsigned short* aplo = aphi + planeElems;
    float* kb = (float*)(aplo + planeElems);
    unsigned short* whi = (unsigned short*)(kb + planeElems);
    unsigned short* wlo = whi + (size_t)C_ * C_;
    float* vb = xt;            // alias: xt dead after last mixsplit
    float* rb = out;           // r lives in d_out until consumed by WKV
    // chend (1MB) aliases the W-plane region: dead between v-GEMM and Wo wconv
    float* chend = (float*)whi;

    const int msBlocks = (int)(planeElems / 4) / 256;   // 16384
    const int wcBlocks = (C_ * C_ / 4) / 256;           // 4096
    const dim3 wkvGrid(C_ / 512, NCH, B_);

    // 1. LayerNorm
    ln_kernel<<<M_, 256, 0, stream>>>(x, ln_w, ln_b, xt);

    // 2. r projection first (output -> d_out)
    mixsplit_kernel<<<msBlocks, 256, 0, stream>>>(xt, mix_r, aphi, aplo);
    wconv_kernel<<<wcBlocks, 256, 0, stream>>>(Wr, whi, wlo);
    gemm_mfma<true><<<256, 512, 0, stream>>>(aphi, aplo, whi, wlo, rb);

    // 3. k projection
    mixsplit_kernel<<<msBlocks, 256, 0, stream>>>(xt, mix_k, aphi, aplo);
    wconv_kernel<<<wcBlocks, 256, 0, stream>>>(Wk, whi, wlo);
    gemm_mfma<false><<<256, 512, 0, stream>>>(aphi, aplo, whi, wlo, kb);

    // 4. v projection (last reader of xt; output overwrites xt region)
    mixsplit_kernel<<<msBlocks, 256, 0, stream>>>(xt, mix_v, aphi, aplo);
    wconv_kernel<<<wcBlocks, 256, 0, stream>>>(Wv, whi, wlo);
    gemm_mfma<false><<<256, 512, 0, stream>>>(aphi, aplo, whi, wlo, vb);

    // 5. WKV chunked scan -> split planes (A-plane region free; chend in W region)
    wkv_scan1<<<wkvGrid, 256, 0, stream>>>(kb, time_decay, chend);
    wkv_scan2<<<wkvGrid, 256, 0, stream>>>(kb, vb, rb, time_decay, time_first, chend,
                                           aphi, aplo);

    // 6. output projection (wconv overwrites chend only after scan2 done)
    wconv_kernel<<<wcBlocks, 256, 0, stream>>>(Wo, whi, wlo);
    gemm_mfma<false><<<256, 512, 0, stream>>>(aphi, aplo, whi, wlo, out);
}

// Round 8
// 769.954 us; speedup vs baseline: 1.1495x; 1.1495x over previous
//
#include <hip/hip_runtime.h>
#include <math.h>

// RWKV6 block on MI355X. fp32 problem; GEMMs via split-bf16 (hi/lo) x3 MFMA emulation
// on mfma_f32_16x16x32_bf16 (R6-proven). B=4, T=2048, C=2048.
// LN + 3x time-mix + bf16-split fused into one kernel (xt never materialized).
// WKV recurrence via chunked parallel scan (32 chunks of 64).
constexpr int B_ = 4;
constexpr int T_ = 2048;
constexpr int C_ = 2048;
constexpr int M_ = B_ * T_;          // 8192 rows
constexpr float EPS_ = 1e-5f;
constexpr int KSTEPS = C_ / 32;      // 64
constexpr int NCH = 32;              // scan chunks
constexpr int CHL = T_ / NCH;        // 64 steps/chunk

typedef __attribute__((ext_vector_type(8))) short short8;   // bf16x8 MFMA operand
typedef __attribute__((ext_vector_type(4))) float f32x4;    // MFMA acc

__device__ __forceinline__ unsigned short rne_bf16(float x) {
    unsigned u = __float_as_uint(x);
    unsigned r = u + 0x7FFFu + ((u >> 16) & 1u);
    return (unsigned short)(r >> 16);
}
__device__ __forceinline__ void split_bf16(float x, unsigned short& hi, unsigned short& lo) {
    hi = rne_bf16(x);
    lo = rne_bf16(x - __uint_as_float((unsigned)hi << 16));
}

// -------- fused LayerNorm (rows m, m-1) + 3x time-mix + split: one block/row ----
__global__ __launch_bounds__(256) void ln_mix3_kernel(
        const float* __restrict__ x,
        const float* __restrict__ w,
        const float* __restrict__ bias,
        const float* __restrict__ mxk,
        const float* __restrict__ mxv,
        const float* __restrict__ mxr,
        unsigned short* __restrict__ khi, unsigned short* __restrict__ klo,
        unsigned short* __restrict__ vhi, unsigned short* __restrict__ vlo,
        unsigned short* __restrict__ rhi, unsigned short* __restrict__ rlo) {
    const int m = blockIdx.x;
    const int tid = threadIdx.x;
    const bool hasPrev = (m & (T_ - 1)) != 0;
    const float* xm = x + (size_t)m * C_;

    float4 a0 = ((const float4*)xm)[tid];
    float4 a1 = ((const float4*)xm)[tid + 256];
    float4 p0 = make_float4(0.f, 0.f, 0.f, 0.f), p1 = p0;
    if (hasPrev) {
        p0 = ((const float4*)(xm - C_))[tid];
        p1 = ((const float4*)(xm - C_))[tid + 256];
    }

    float sm = a0.x + a0.y + a0.z + a0.w + a1.x + a1.y + a1.z + a1.w;
    float qm = a0.x*a0.x + a0.y*a0.y + a0.z*a0.z + a0.w*a0.w
             + a1.x*a1.x + a1.y*a1.y + a1.z*a1.z + a1.w*a1.w;
    float sp = p0.x + p0.y + p0.z + p0.w + p1.x + p1.y + p1.z + p1.w;
    float qp = p0.x*p0.x + p0.y*p0.y + p0.z*p0.z + p0.w*p0.w
             + p1.x*p1.x + p1.y*p1.y + p1.z*p1.z + p1.w*p1.w;

    #pragma unroll
    for (int off = 32; off > 0; off >>= 1) {
        sm += __shfl_down(sm, off, 64);
        qm += __shfl_down(qm, off, 64);
        sp += __shfl_down(sp, off, 64);
        qp += __shfl_down(qp, off, 64);
    }
    __shared__ float red[20];
    const int wid = tid >> 6, lane = tid & 63;
    if (lane == 0) {
        red[wid * 4 + 0] = sm; red[wid * 4 + 1] = qm;
        red[wid * 4 + 2] = sp; red[wid * 4 + 3] = qp;
    }
    __syncthreads();
    if (tid == 0) {
        float tsm = 0.f, tqm = 0.f, tsp = 0.f, tqp = 0.f;
        #pragma unroll
        for (int i = 0; i < 4; ++i) {
            tsm += red[i * 4 + 0]; tqm += red[i * 4 + 1];
            tsp += red[i * 4 + 2]; tqp += red[i * 4 + 3];
        }
        const float mum = tsm / (float)C_;
        const float varm = tqm / (float)C_ - mum * mum;
        const float mup = tsp / (float)C_;
        const float varp = tqp / (float)C_ - mup * mup;
        red[16] = mum; red[17] = rsqrtf(varm + EPS_);
        red[18] = mup; red[19] = rsqrtf(varp + EPS_);
    }
    __syncthreads();
    const float mum = red[16], rsm = red[17];
    const float mup = red[18], rsp = red[19];

    float4 w0 = ((const float4*)w)[tid];
    float4 w1 = ((const float4*)w)[tid + 256];
    float4 b0 = ((const float4*)bias)[tid];
    float4 b1 = ((const float4*)bias)[tid + 256];

    const float av[8] = {a0.x, a0.y, a0.z, a0.w, a1.x, a1.y, a1.z, a1.w};
    const float pv[8] = {p0.x, p0.y, p0.z, p0.w, p1.x, p1.y, p1.z, p1.w};
    const float wv[8] = {w0.x, w0.y, w0.z, w0.w, w1.x, w1.y, w1.z, w1.w};
    const float bv[8] = {b0.x, b0.y, b0.z, b0.w, b1.x, b1.y, b1.z, b1.w};

    float lm[8], lp[8];
    #pragma unroll
    for (int j = 0; j < 8; ++j) {
        lm[j] = (av[j] - mum) * rsm * wv[j] + bv[j];
        lp[j] = hasPrev ? (pv[j] - mup) * rsp * wv[j] + bv[j] : 0.f;  // prev=0 at t=0
    }

    const size_t rowbase = (size_t)m * C_;
    auto emit = [&](const float* __restrict__ mx,
                    unsigned short* __restrict__ hi,
                    unsigned short* __restrict__ lo) {
        float4 m0 = ((const float4*)mx)[tid];
        float4 m1 = ((const float4*)mx)[tid + 256];
        const float mm[8] = {m0.x, m0.y, m0.z, m0.w, m1.x, m1.y, m1.z, m1.w};
        ushort4 h[2], l[2];
        #pragma unroll
        for (int half = 0; half < 2; ++half) {
            unsigned short hh[4], ll[4];
            #pragma unroll
            for (int j = 0; j < 4; ++j) {
                const int c = half * 4 + j;
                const float a = lp[c] + (lm[c] - lp[c]) * mm[c];
                split_bf16(a, hh[j], ll[j]);
            }
            h[half].x = hh[0]; h[half].y = hh[1]; h[half].z = hh[2]; h[half].w = hh[3];
            l[half].x = ll[0]; l[half].y = ll[1]; l[half].z = ll[2]; l[half].w = ll[3];
        }
        ((ushort4*)(hi + rowbase))[tid] = h[0];
        ((ushort4*)(hi + rowbase))[tid + 256] = h[1];
        ((ushort4*)(lo + rowbase))[tid] = l[0];
        ((ushort4*)(lo + rowbase))[tid + 256] = l[1];
    };
    emit(mxk, khi, klo);
    emit(mxv, vhi, vlo);
    emit(mxr, rhi, rlo);
}

// ---------------- W fp32 -> (hi, lo) bf16 planes ----------------
__global__ __launch_bounds__(256) void wconv_kernel(const float* __restrict__ W,
                                                    unsigned short* __restrict__ hi,
                                                    unsigned short* __restrict__ lo) {
    const int i = blockIdx.x * 256 + threadIdx.x;   // over C_*C_/4 float4s
    float4 w = ((const float4*)W)[i];
    ushort4 h, l;
    split_bf16(w.x, h.x, l.x);
    split_bf16(w.y, h.y, l.y);
    split_bf16(w.z, h.z, l.z);
    split_bf16(w.w, h.w, l.w);
    ((ushort4*)hi)[i] = h;
    ((ushort4*)lo)[i] = l;
}

// ---------------- MFMA GEMM: Y[m,n] = sum_k A[m,k] * W[n,k] --------------
// acc += Ah*Wh + Al*Wh + Ah*Wl. 256x256 tile, BK=32, 512 threads (8 waves,
// 2Mx4N). 128KB LDS double-buffer; per region 256 rows x 8 slots of 16B,
// physical slot p = s ^ (row&7) (conflict-free); global_load_lds dest linear,
// per-lane GLOBAL source pre-applies the inverse swizzle.
// 4 phases per K-step (one mi-pair each, 24 MFMA), counted vmcnt, setprio.
template <bool SIG>
__global__ __launch_bounds__(512, 2) void gemm_mfma(const unsigned short* __restrict__ Ahi,
                                                    const unsigned short* __restrict__ Alo,
                                                    const unsigned short* __restrict__ Whi,
                                                    const unsigned short* __restrict__ Wlo,
                                                    float* __restrict__ Y) {
    __shared__ unsigned short lds[2][2][256 * 64];

    const int tid = threadIdx.x;
    const int lane = tid & 63;
    const int wid = tid >> 6;          // 0..7
    const int wr = wid >> 2;           // 0..1  (M half: 128 rows)
    const int wcn = wid & 3;           // 0..3  (N quarter: 64 cols)

    // XCD-chunked block swizzle: 256 blocks, 8 XCDs, 32/XCD
    const int bid = blockIdx.x;
    const int swz = (bid & 7) * 32 + (bid >> 3);
    const int m0 = (swz >> 3) * 256;
    const int n0 = (swz & 7) * 256;

    const unsigned short* gA[4];
    const unsigned short* gB[4];
    #pragma unroll
    for (int j = 0; j < 4; ++j) {
        const int ci = j * 512 + tid;
        const int r = ci >> 3, p = ci & 7;
        const int s = p ^ (r & 7);
        const int pl = s >> 2, ks = s & 3;
        gA[j] = (pl ? Alo : Ahi) + (size_t)(m0 + r) * C_ + ks * 8;
        gB[j] = (pl ? Wlo : Whi) + (size_t)(n0 + r) * C_ + ks * 8;
    }
    const int stage_off = wid * 512;

    const int fr = lane & 15;
    const int kg = lane >> 4;
    const int pH = (kg + 0) ^ (fr & 7);
    const int pL = (kg + 4) ^ (fr & 7);
    const int baseA0 = (wr * 128 + fr) * 64 + pH * 8;
    const int baseA1 = (wr * 128 + fr) * 64 + pL * 8;
    const int baseB0 = (wcn * 64 + fr) * 64 + pH * 8;
    const int baseB1 = (wcn * 64 + fr) * 64 + pL * 8;

    f32x4 acc[8][4] = {};

    auto ISSUE = [&](int buf, int t, int j) {
        const int ko = t * 32;
        __builtin_amdgcn_global_load_lds(
            (const __attribute__((address_space(1))) unsigned int*)(gA[j] + ko),
            (__attribute__((address_space(3))) unsigned int*)&lds[buf][0][j * 4096 + stage_off],
            16, 0, 0);
        __builtin_amdgcn_global_load_lds(
            (const __attribute__((address_space(1))) unsigned int*)(gB[j] + ko),
            (__attribute__((address_space(3))) unsigned int*)&lds[buf][1][j * 4096 + stage_off],
            16, 0, 0);
    };

    // prologue: stage tile 0 (8 loads/thread)
    #pragma unroll
    for (int j = 0; j < 4; ++j) ISSUE(0, 0, j);

    for (int t = 0; t < KSTEPS; ++t) {
        const int cur = t & 1, nxt = cur ^ 1;
        const bool last = (t == KSTEPS - 1);
        const unsigned short* LA = lds[cur][0];
        const unsigned short* LB = lds[cur][1];

        short8 bh[4], bl[4];

        // ---------- phase 0 (mi 0,1): validate buf cur, read B frags ----------
        if (!last) {
            ISSUE(nxt, t + 1, 0);
            asm volatile("s_waitcnt vmcnt(2)" ::: "memory");  // tile t's 8 done
        } else {
            asm volatile("s_waitcnt vmcnt(0)" ::: "memory");
        }
        __builtin_amdgcn_s_barrier();
        #pragma unroll
        for (int ni = 0; ni < 4; ++ni) {
            bh[ni] = *(const short8*)&LB[baseB0 + ni * 1024];
            bl[ni] = *(const short8*)&LB[baseB1 + ni * 1024];
        }
        {
            const short8 a0h = *(const short8*)&LA[baseA0 + 0 * 1024];
            const short8 a0l = *(const short8*)&LA[baseA1 + 0 * 1024];
            const short8 a1h = *(const short8*)&LA[baseA0 + 1 * 1024];
            const short8 a1l = *(const short8*)&LA[baseA1 + 1 * 1024];
            asm volatile("s_waitcnt lgkmcnt(0)" ::: "memory");
            __builtin_amdgcn_s_setprio(1);
            #pragma unroll
            for (int ni = 0; ni < 4; ++ni) {
                acc[0][ni] = __builtin_amdgcn_mfma_f32_16x16x32_bf16(a0h, bh[ni], acc[0][ni], 0, 0, 0);
                acc[0][ni] = __builtin_amdgcn_mfma_f32_16x16x32_bf16(a0l, bh[ni], acc[0][ni], 0, 0, 0);
                acc[0][ni] = __builtin_amdgcn_mfma_f32_16x16x32_bf16(a0h, bl[ni], acc[0][ni], 0, 0, 0);
                acc[1][ni] = __builtin_amdgcn_mfma_f32_16x16x32_bf16(a1h, bh[ni], acc[1][ni], 0, 0, 0);
                acc[1][ni] = __builtin_amdgcn_mfma_f32_16x16x32_bf16(a1l, bh[ni], acc[1][ni], 0, 0, 0);
                acc[1][ni] = __builtin_amdgcn_mfma_f32_16x16x32_bf16(a1h, bl[ni], acc[1][ni], 0, 0, 0);
            }
            __builtin_amdgcn_s_setprio(0);
        }
        __builtin_amdgcn_s_barrier();

        // ---------- phases 1..3 (mi-pairs 2-3, 4-5, 6-7) ----------
        #pragma unroll
        for (int p = 1; p < 4; ++p) {
            const int mi0 = 2 * p;
            const short8 a0h = *(const short8*)&LA[baseA0 + mi0 * 1024];
            const short8 a0l = *(const short8*)&LA[baseA1 + mi0 * 1024];
            const short8 a1h = *(const short8*)&LA[baseA0 + (mi0 + 1) * 1024];
            const short8 a1l = *(const short8*)&LA[baseA1 + (mi0 + 1) * 1024];
            if (!last) ISSUE(nxt, t + 1, p);
            __builtin_amdgcn_s_barrier();
            asm volatile("s_waitcnt lgkmcnt(0)" ::: "memory");
            __builtin_amdgcn_s_setprio(1);
            #pragma unroll
            for (int ni = 0; ni < 4; ++ni) {
                acc[mi0][ni]     = __builtin_amdgcn_mfma_f32_16x16x32_bf16(a0h, bh[ni], acc[mi0][ni], 0, 0, 0);
                acc[mi0][ni]     = __builtin_amdgcn_mfma_f32_16x16x32_bf16(a0l, bh[ni], acc[mi0][ni], 0, 0, 0);
                acc[mi0][ni]     = __builtin_amdgcn_mfma_f32_16x16x32_bf16(a0h, bl[ni], acc[mi0][ni], 0, 0, 0);
                acc[mi0 + 1][ni] = __builtin_amdgcn_mfma_f32_16x16x32_bf16(a1h, bh[ni], acc[mi0 + 1][ni], 0, 0, 0);
                acc[mi0 + 1][ni] = __builtin_amdgcn_mfma_f32_16x16x32_bf16(a1l, bh[ni], acc[mi0 + 1][ni], 0, 0, 0);
                acc[mi0 + 1][ni] = __builtin_amdgcn_mfma_f32_16x16x32_bf16(a1h, bl[ni], acc[mi0 + 1][ni], 0, 0, 0);
            }
            __builtin_amdgcn_s_setprio(0);
            __builtin_amdgcn_s_barrier();
        }
    }

    // ---- epilogue: C/D layout col=lane&15, row=(lane>>4)*4+reg ----
    const int orow = m0 + wr * 128 + (lane >> 4) * 4;
    const int ocol = n0 + wcn * 64 + fr;
    #pragma unroll
    for (int mi = 0; mi < 8; ++mi)
        #pragma unroll
        for (int ni = 0; ni < 4; ++ni)
            #pragma unroll
            for (int rr = 0; rr < 4; ++rr) {
                float v = acc[mi][ni][rr];
                if (SIG) v = 1.f / (1.f + expf(-v));
                Y[(size_t)(orow + mi * 16 + rr) * C_ + ocol + ni * 16] = v;
            }
}

// ---------------- WKV chunked scan, pass 1: per-chunk local end state ----
__global__ __launch_bounds__(256) void wkv_scan1(const float* __restrict__ k,
                                                 const float* __restrict__ time_decay,
                                                 float* __restrict__ chend) {
    const int c0 = (blockIdx.x * 256 + threadIdx.x) * 2;
    const int j = blockIdx.y;
    const int b = blockIdx.z;
    const float2 td = *(const float2*)&time_decay[c0];
    const float d0 = 1.f / (1.f + expf(-td.x));
    const float d1 = 1.f / (1.f + expf(-td.y));
    size_t base = ((size_t)b * T_ + (size_t)j * CHL) * C_ + c0;
    float s0 = 0.f, s1 = 0.f;
    #pragma unroll 8
    for (int t = 0; t < CHL; ++t) {
        const float2 kt = *(const float2*)&k[base];
        s0 = s0 * d0 + kt.x;
        s1 = s1 * d1 + kt.y;
        base += C_;
    }
    *(float2*)&chend[((size_t)b * NCH + j) * C_ + c0] = make_float2(s0, s1);
}

// ---------------- WKV chunked scan, pass 2: carry-in + rescan + fuse -----
__global__ __launch_bounds__(256) void wkv_scan2(const float* __restrict__ k,
                                                 const float* __restrict__ v,
                                                 const float* __restrict__ r,
                                                 const float* __restrict__ time_decay,
                                                 const float* __restrict__ time_first,
                                                 const float* __restrict__ chend,
                                                 unsigned short* __restrict__ yhi,
                                                 unsigned short* __restrict__ ylo) {
    const int c0 = (blockIdx.x * 256 + threadIdx.x) * 2;
    const int j = blockIdx.y;
    const int b = blockIdx.z;
    const float2 td = *(const float2*)&time_decay[c0];
    const float2 tf = *(const float2*)&time_first[c0];
    const float d0 = 1.f / (1.f + expf(-td.x));
    const float d1 = 1.f / (1.f + expf(-td.y));
    const float f0 = expf(tf.x);
    const float f1 = expf(tf.y);

    float dL0 = d0, dL1 = d1;           // d^CHL, CHL=64 -> 6 squarings
    #pragma unroll
    for (int i = 0; i < 6; ++i) { dL0 *= dL0; dL1 *= dL1; }

    float s0 = 0.f, s1 = 0.f;
    for (int i = 0; i < j; ++i) {
        const float2 e = *(const float2*)&chend[((size_t)b * NCH + i) * C_ + c0];
        s0 = s0 * dL0 + e.x;
        s1 = s1 * dL1 + e.y;
    }

    size_t base = ((size_t)b * T_ + (size_t)j * CHL) * C_ + c0;
    #pragma unroll 4
    for (int t = 0; t < CHL; ++t) {
        const float2 kt = *(const float2*)&k[base];
        const float2 vt = *(const float2*)&v[base];
        const float2 rt = *(const float2*)&r[base];
        s0 = s0 * d0 + kt.x;
        s1 = s1 * d1 + kt.y;
        const float y0 = rt.x * ((s0 * f0 + kt.x) * vt.x);
        const float y1 = rt.y * ((s1 * f1 + kt.y) * vt.y);
        unsigned short h0, l0, h1, l1;
        split_bf16(y0, h0, l0);
        split_bf16(y1, h1, l1);
        ushort2 ph; ph.x = h0; ph.y = h1;
        ushort2 pl; pl.x = l0; pl.y = l1;
        *(ushort2*)&yhi[base] = ph;
        *(ushort2*)&ylo[base] = pl;
        base += C_;
    }
}

// ---------------- launch ----------------
extern "C" void kernel_launch(void* const* d_in, const int* in_sizes, int n_in,
                              void* d_out, int out_size, void* d_ws, size_t ws_size,
                              hipStream_t stream) {
    const float* x          = (const float*)d_in[0];
    const float* ln_w       = (const float*)d_in[1];
    const float* ln_b       = (const float*)d_in[2];
    const float* mix_k      = (const float*)d_in[3];
    const float* mix_v      = (const float*)d_in[4];
    const float* mix_r      = (const float*)d_in[5];
    const float* time_decay = (const float*)d_in[6];
    const float* time_first = (const float*)d_in[7];
    const float* Wk         = (const float*)d_in[8];
    const float* Wv         = (const float*)d_in[9];
    const float* Wr         = (const float*)d_in[10];
    const float* Wo         = (const float*)d_in[11];
    float* out = (float*)d_out;

    // ws (208 MiB): R0 Ak(hi+lo) 64 | R1 Av 64 | R2 Ar 64 | R3 W planes 16
    // Aliases (sequential stream, no overlap within a kernel):
    //   kb -> R2 (Ar dead after r-GEMM); vb -> R0 (Ak dead after k-GEMM);
    //   y planes -> R1 (Av dead after v-GEMM); chend -> R3 (W dead between
    //   v-GEMM and Wo wconv); rb -> d_out (consumed by scan2 before out-GEMM).
    const size_t planeElems = (size_t)M_ * C_;
    unsigned short* akhi = (unsigned short*)d_ws;
    unsigned short* aklo = akhi + planeElems;
    unsigned short* avhi = aklo + planeElems;
    unsigned short* avlo = avhi + planeElems;
    unsigned short* arhi = avlo + planeElems;
    unsigned short* arlo = arhi + planeElems;
    unsigned short* whi  = arlo + planeElems;
    unsigned short* wlo  = whi + (size_t)C_ * C_;

    float* kb = (float*)arhi;
    float* vb = (float*)akhi;
    float* rb = out;
    unsigned short* yhi = avhi;
    unsigned short* ylo = avlo;
    float* chend = (float*)whi;

    const int wcBlocks = (C_ * C_ / 4) / 256;           // 4096
    const dim3 wkvGrid(C_ / 512, NCH, B_);

    // 1. fused LN + 3x mix + split (writes all three A-plane pairs)
    ln_mix3_kernel<<<M_, 256, 0, stream>>>(x, ln_w, ln_b, mix_k, mix_v, mix_r,
                                           akhi, aklo, avhi, avlo, arhi, arlo);

    // 2. r projection (sigmoid fused) -> d_out
    wconv_kernel<<<wcBlocks, 256, 0, stream>>>(Wr, whi, wlo);
    gemm_mfma<true><<<256, 512, 0, stream>>>(arhi, arlo, whi, wlo, rb);

    // 3. k projection -> kb (over Ar region)
    wconv_kernel<<<wcBlocks, 256, 0, stream>>>(Wk, whi, wlo);
    gemm_mfma<false><<<256, 512, 0, stream>>>(akhi, aklo, whi, wlo, kb);

    // 4. v projection -> vb (over Ak region)
    wconv_kernel<<<wcBlocks, 256, 0, stream>>>(Wv, whi, wlo);
    gemm_mfma<false><<<256, 512, 0, stream>>>(avhi, avlo, whi, wlo, vb);

    // 5. WKV chunked scan -> y planes (over Av region; chend over W region)
    wkv_scan1<<<wkvGrid, 256, 0, stream>>>(kb, time_decay, chend);
    wkv_scan2<<<wkvGrid, 256, 0, stream>>>(kb, vb, rb, time_decay, time_first, chend,
                                           yhi, ylo);

    // 6. output projection (wconv overwrites chend only after scan2 done)
    wconv_kernel<<<wcBlocks, 256, 0, stream>>>(Wo, whi, wlo);
    gemm_mfma<false><<<256, 512, 0, stream>>>(yhi, ylo, whi, wlo, out);
}